// Round 1
// baseline (269.719 us; speedup 1.0000x reference)
//
#include <hip/hip_runtime.h>

// ChannelBlockImportanceGate: B=8, C=256, H=W=132, BLOCK=8, KEEP_RATIO=0.25
// Output = hard top-72 block mask (of 289 blocks) upsampled 8x, per (b,c) plane.
// Straight-through soft blend cancels numerically -> output is the hard mask.

#define HH 132
#define WW 132
#define NB 17          // blocks per side (ceil(132/8) = 17)
#define TOTAL 289      // NB*NB
#define KEEP 72        // round(289*0.25)
#define NTHREADS 256

__global__ __launch_bounds__(NTHREADS)
void gate_kernel(const float* __restrict__ feats,
                 const int* __restrict__ enabled_p,
                 float* __restrict__ out) {
    const int plane = blockIdx.x;            // b*C + c, 0..2047
    const int t = threadIdx.x;
    const float* __restrict__ fp = feats + (size_t)plane * (HH * WW);
    float* __restrict__ op = out + (size_t)plane * (HH * WW);

    __shared__ double s_col[WW];             // per-column stripe sums
    __shared__ double s_score[TOTAL];        // block sums (fp64-exact)
    __shared__ float  s_hard[TOTAL];         // 0/1 mask per block

    // ---- Phase 1: block sums of |x|, fp64 accumulation ----
    for (int br = 0; br < NB; ++br) {
        const int r0 = br * 8;
        const int nr = (r0 + 8 <= HH) ? 8 : (HH - r0);   // 8, last stripe 4
        if (t < WW) {
            double acc = 0.0;
            const float* rp = fp + (size_t)r0 * WW + t;
            #pragma unroll
            for (int k = 0; k < 8; ++k) {
                if (k < nr) acc += (double)fabsf(rp[k * WW]);
            }
            s_col[t] = acc;
        }
        __syncthreads();
        if (t < NB) {
            const int c0 = t * 8;
            const int nc = (c0 + 8 <= WW) ? 8 : (WW - c0); // 8, last block-col 4
            double s = 0.0;
            for (int j = 0; j < nc; ++j) s += s_col[c0 + j];
            s_score[br * NB + t] = s;        // mean = s/64, monotone -> skip divide
        }
        __syncthreads();
    }

    // ---- Phase 2: top-72 selection by stable rank (matches lax.top_k ties) ----
    const int en = *enabled_p;
    for (int i = t; i < TOTAL; i += NTHREADS) {
        const double si = s_score[i];
        int rank = 0;
        for (int j = 0; j < TOTAL; ++j) {    // broadcast LDS reads, no conflicts
            const double sj = s_score[j];
            rank += (int)((sj > si) || ((sj == si) && (j < i)));
        }
        s_hard[i] = (!en || rank < KEEP) ? 1.0f : 0.0f;
    }
    __syncthreads();

    // ---- Phase 3: upsample 8x and store. 132%4==0 and 4-aligned quads never
    // cross an 8-wide block boundary -> one mask value per float4. ----
    constexpr int NV = (HH * WW) / 4;        // 4356 float4s per plane
    float4* __restrict__ op4 = (float4*)op;
    for (int v = t; v < NV; v += NTHREADS) {
        const int base = v * 4;
        const int row = base / WW;           // magic-mul division by 132
        const int col = base - row * WW;
        const float m = s_hard[(row >> 3) * NB + (col >> 3)];
        op4[v] = make_float4(m, m, m, m);
    }
}

extern "C" void kernel_launch(void* const* d_in, const int* in_sizes, int n_in,
                              void* d_out, int out_size, void* d_ws, size_t ws_size,
                              hipStream_t stream) {
    const float* feats = (const float*)d_in[0];
    const int* enabled = (const int*)d_in[1];
    float* out = (float*)d_out;
    const int planes = 8 * 256;              // B*C = 2048
    gate_kernel<<<planes, NTHREADS, 0, stream>>>(feats, enabled, out);
}